// Round 1
// 602.661 us; speedup vs baseline: 1.1864x; 1.1864x over previous
//
#include <hip/hip_runtime.h>
#include <math.h>

#define DIMC 1024
#define C2   2048
#define DR   256
#define DH   32
#define NE   4
#define NB   8
#define NN   2048
#define NM   16384   /* NB*NN */

typedef short bf16x8 __attribute__((ext_vector_type(8)));
typedef float f32x4  __attribute__((ext_vector_type(4)));

__device__ __forceinline__ unsigned short f2bf(float f) {
    union { float f; unsigned int u; } v; v.f = f;
    unsigned int r = v.u + 0x7fffu + ((v.u >> 16) & 1u);   /* RNE */
    return (unsigned short)(r >> 16);
}

/* =====================  K0: prep  W''[c][k] = bf16(g_k * W[k][c]),
   u[c] = sum_k g_k W[k][c],  beta[c] = sum_k b_k W[k][c]  ===================== */
__global__ __launch_bounds__(256) void k_prep(
    const float* __restrict__ wred, const float* __restrict__ g1,
    const float* __restrict__ b1v, unsigned short* __restrict__ wpp,
    float* __restrict__ u, float* __restrict__ beta)
{
    __shared__ unsigned short tsh[64][72];
    __shared__ float ush[64], bsh[64];
    const int tid = threadIdx.x;
    const int k0 = (blockIdx.x >> 2) * 64;   /* 32 k-tiles */
    const int c0 = (blockIdx.x & 3) * 64;    /* 4 c-tiles  */
    if (tid < 64) { ush[tid] = 0.f; bsh[tid] = 0.f; }
    __syncthreads();

    const int r = tid >> 2, cs = (tid & 3) * 16;
    const float gk = g1[k0 + r], bk = b1v[k0 + r];
#pragma unroll
    for (int i = 0; i < 4; ++i) {
        float4 wv = *(const float4*)(wred + (size_t)(k0 + r) * DR + c0 + cs + i * 4);
        const int cb = cs + i * 4;
        atomicAdd(&ush[cb + 0], gk * wv.x); atomicAdd(&ush[cb + 1], gk * wv.y);
        atomicAdd(&ush[cb + 2], gk * wv.z); atomicAdd(&ush[cb + 3], gk * wv.w);
        atomicAdd(&bsh[cb + 0], bk * wv.x); atomicAdd(&bsh[cb + 1], bk * wv.y);
        atomicAdd(&bsh[cb + 2], bk * wv.z); atomicAdd(&bsh[cb + 3], bk * wv.w);
        tsh[cb + 0][r] = f2bf(gk * wv.x);
        tsh[cb + 1][r] = f2bf(gk * wv.y);
        tsh[cb + 2][r] = f2bf(gk * wv.z);
        tsh[cb + 3][r] = f2bf(gk * wv.w);
    }
    __syncthreads();

    const int cc = tid >> 2, seg = (tid & 3) * 16;
    uint4 v0 = *(const uint4*)&tsh[cc][seg];
    uint4 v1 = *(const uint4*)&tsh[cc][seg + 8];
    unsigned short* dst = wpp + (size_t)(c0 + cc) * C2 + k0 + seg;
    *(uint4*)(dst)     = v0;
    *(uint4*)(dst + 8) = v1;
    if (tid < 64) {
        atomicAdd(&u[c0 + tid],    ush[tid]);
        atomicAdd(&beta[c0 + tid], bsh[tid]);
    }
}

/* =====================  K1: MFMA front — y = r*(v@W'') - r*mu*u + beta, then LN2.
   m97-style 2-phase pipeline: FT=32 (grid 512, 2 blocks/CU), B via global_load_lds
   (double-buffered, XOR-swizzled source + read), A reg-staged with fused LN1 stats,
   one barrier per K-chunk.  ===================== */
#define FT   32
#define FBK  64
#define LDA  72
#define NCH  32

#define GLDS(gp, lo) __builtin_amdgcn_global_load_lds( \
    (const __attribute__((address_space(1))) unsigned int*)(unsigned long long)(gp), \
    (__attribute__((address_space(3))) unsigned int*)(unsigned int)(unsigned long long)(lo), \
    16, 0, 0)

__global__ __launch_bounds__(256, 2) void k_front(
    const float* __restrict__ x, const float* __restrict__ t,
    const unsigned short* __restrict__ wpp,
    const float* __restrict__ u, const float* __restrict__ beta,
    const float* __restrict__ ln2g, const float* __restrict__ ln2b,
    float* __restrict__ yf)
{
    __shared__ __attribute__((aligned(16))) unsigned short A_sh[2][FT * LDA];   /* 9216 B  */
    __shared__ __attribute__((aligned(16))) unsigned short B_sh[2][DR * FBK];   /* 65536 B */
    __shared__ float us_sh[DR], be_sh[DR], g2_sh[DR], b2_sh[DR];
    __shared__ float mean_sh[FT], rstd_sh[FT];
    __shared__ float pls[FT][4], plss[FT][4];

    const int tid  = threadIdx.x;
    const int m0   = blockIdx.x * FT;
    const int lane = tid & 63;
    const int w    = tid >> 6;               /* wave: owns 64-col slice, stages 64 B-rows */
    const int cl   = lane & 15, kg = lane >> 4;

    if (tid < DR) {
        us_sh[tid] = u[tid];   be_sh[tid] = beta[tid];
        g2_sh[tid] = ln2g[tid]; b2_sh[tid] = ln2b[tid];
    }

    /* A staging map: 8 threads per token, 8 floats each */
    const int atok = tid >> 3;               /* 0..31 */
    const int aks  = (tid & 7) * 8;          /* 0..56 */

    /* B staging map (global_load_lds, pre-swizzled global source):
       wave w stages rows [w*64, w*64+64); instr i covers 8 rows (1 KB).
       LDS linear byte p = w*8192 + i*1024 + lane*16  ->  row r = p>>7,
       swizzle: LDS[p] holds global 16B-slot s = (lane&7) ^ (lane>>3) of row r. */
    const int brow  = w * 64 + (lane >> 3);
    const int bslot = (lane & 7) ^ (lane >> 3);
    const unsigned char* wppB =
        (const unsigned char*)wpp + (size_t)brow * 4096 + (size_t)bslot * 16;
    const unsigned long long ldsB =
        (unsigned long long)(const void*)&B_sh[0][0] + (unsigned)(w * 8192);

    float s1 = 0.f, ss1 = 0.f;
    f32x4 acc[2][4];
#pragma unroll
    for (int rt = 0; rt < 2; ++rt)
#pragma unroll
        for (int ct = 0; ct < 4; ++ct) acc[rt][ct] = (f32x4){0.f, 0.f, 0.f, 0.f};

    float4 nax0, nax1;

#define STAGE(KN, BUF) do { \
        const float* _src = ((KN) < 16) ? x : t; \
        const float* _ar = _src + (size_t)(m0 + atok) * DIMC + ((KN) & 15) * FBK + aks; \
        nax0 = *(const float4*)_ar; nax1 = *(const float4*)(_ar + 4); \
        _Pragma("unroll") \
        for (int _i = 0; _i < 8; ++_i) \
            GLDS(wppB + (size_t)_i * 8 * 4096 + (KN) * 128, \
                 ldsB + (unsigned)((BUF) * 32768 + _i * 1024)); \
    } while (0)

#define CVT(BUF) do { \
        float4 _v = nax0; \
        s1 += _v.x + _v.y + _v.z + _v.w; \
        ss1 += _v.x*_v.x + _v.y*_v.y + _v.z*_v.z + _v.w*_v.w; \
        short4 _p; \
        _p.x = (short)f2bf(_v.x); _p.y = (short)f2bf(_v.y); \
        _p.z = (short)f2bf(_v.z); _p.w = (short)f2bf(_v.w); \
        *(short4*)&A_sh[BUF][atok * LDA + aks] = _p; \
        _v = nax1; \
        s1 += _v.x + _v.y + _v.z + _v.w; \
        ss1 += _v.x*_v.x + _v.y*_v.y + _v.z*_v.z + _v.w*_v.w; \
        _p.x = (short)f2bf(_v.x); _p.y = (short)f2bf(_v.y); \
        _p.z = (short)f2bf(_v.z); _p.w = (short)f2bf(_v.w); \
        *(short4*)&A_sh[BUF][atok * LDA + aks + 4] = _p; \
    } while (0)

#define MFMA_PHASE(BUF) do { \
        _Pragma("unroll") \
        for (int kk = 0; kk < 2; ++kk) { \
            bf16x8 af0 = *(const bf16x8*)&A_sh[BUF][(cl)      * LDA + kk * 32 + kg * 8]; \
            bf16x8 af1 = *(const bf16x8*)&A_sh[BUF][(16 + cl) * LDA + kk * 32 + kg * 8]; \
            _Pragma("unroll") \
            for (int ct = 0; ct < 4; ++ct) { \
                const int _r  = w * 64 + ct * 16 + cl; \
                const int _off = (_r * 128 + kk * 64 + kg * 16) ^ ((_r & 7) << 4); \
                bf16x8 bf = *(const bf16x8*)((const char*)&B_sh[BUF][0] + _off); \
                acc[0][ct] = __builtin_amdgcn_mfma_f32_16x16x32_bf16(af0, bf, acc[0][ct], 0, 0, 0); \
                acc[1][ct] = __builtin_amdgcn_mfma_f32_16x16x32_bf16(af1, bf, acc[1][ct], 0, 0, 0); \
            } \
        } \
    } while (0)

    /* prologue: stage chunk 0 into buf 0 */
    STAGE(0, 0);
    CVT(0);
    __syncthreads();

    for (int kc = 0; kc < NCH; kc += 2) {
        /* phase A: stage chunk kc+1 -> buf1 early, compute chunk kc from buf0 */
        STAGE(kc + 1, 1);
        MFMA_PHASE(0);
        CVT(1);
        __syncthreads();
        /* phase B: stage chunk kc+2 -> buf0, compute chunk kc+1 from buf1 */
        if (kc + 2 < NCH) {
            STAGE(kc + 2, 0);
            MFMA_PHASE(1);
            CVT(0);
        } else {
            MFMA_PHASE(1);
        }
        __syncthreads();
    }

    /* LN1 stats reduce: 8 threads per token (consecutive lanes) */
    {
        float s = s1, ss = ss1;
        s += __shfl_xor(s, 1); ss += __shfl_xor(ss, 1);
        s += __shfl_xor(s, 2); ss += __shfl_xor(ss, 2);
        s += __shfl_xor(s, 4); ss += __shfl_xor(ss, 4);
        if ((tid & 7) == 0) {
            float m  = s * (1.f / 2048.f);
            float va = ss * (1.f / 2048.f) - m * m;
            mean_sh[atok] = m;
            rstd_sh[atok] = rsqrtf(va + 1e-5f);
        }
    }
    __syncthreads();

    /* epilogue: LN1 correction, LN2 stats (cross-wave via LDS), write yf */
    float rsum[2][4], rssq[2][4];
#pragma unroll
    for (int rt = 0; rt < 2; ++rt)
#pragma unroll
        for (int reg = 0; reg < 4; ++reg) { rsum[rt][reg] = 0.f; rssq[rt][reg] = 0.f; }

#pragma unroll
    for (int ct = 0; ct < 4; ++ct) {
        const int col = w * 64 + ct * 16 + cl;
        const float uu = us_sh[col], bb = be_sh[col];
#pragma unroll
        for (int rt = 0; rt < 2; ++rt)
#pragma unroll
            for (int reg = 0; reg < 4; ++reg) {
                const int tok = rt * 16 + kg * 4 + reg;
                const float mu = mean_sh[tok], rr = rstd_sh[tok];
                float y = rr * acc[rt][ct][reg] - rr * mu * uu + bb;
                acc[rt][ct][reg] = y;
                rsum[rt][reg] += y; rssq[rt][reg] += y * y;
            }
    }
#pragma unroll
    for (int mask = 1; mask <= 8; mask <<= 1)
#pragma unroll
        for (int rt = 0; rt < 2; ++rt)
#pragma unroll
            for (int reg = 0; reg < 4; ++reg) {
                rsum[rt][reg] += __shfl_xor(rsum[rt][reg], mask);
                rssq[rt][reg] += __shfl_xor(rssq[rt][reg], mask);
            }
    if (cl == 0) {
#pragma unroll
        for (int rt = 0; rt < 2; ++rt)
#pragma unroll
            for (int reg = 0; reg < 4; ++reg) {
                const int tok = rt * 16 + kg * 4 + reg;
                pls[tok][w]  = rsum[rt][reg];
                plss[tok][w] = rssq[rt][reg];
            }
    }
    __syncthreads();

#pragma unroll
    for (int rt = 0; rt < 2; ++rt) {
#pragma unroll
        for (int reg = 0; reg < 4; ++reg) {
            const int tok = rt * 16 + kg * 4 + reg;
            const float m2 = (pls[tok][0] + pls[tok][1] + pls[tok][2] + pls[tok][3]) * (1.f / 256.f);
            const float v2 = (plss[tok][0] + plss[tok][1] + plss[tok][2] + plss[tok][3]) * (1.f / 256.f) - m2 * m2;
            const float r2 = rsqrtf(v2 + 1e-5f);
            float* yr = yf + (size_t)(m0 + tok) * DR;
#pragma unroll
            for (int ct = 0; ct < 4; ++ct) {
                const int col = w * 64 + ct * 16 + cl;
                yr[col] = (acc[rt][ct][reg] - m2) * r2 * g2_sh[col] + b2_sh[col];
            }
        }
    }
#undef STAGE
#undef CVT
#undef MFMA_PHASE
}

/* =====================  K2: MoE (unchanged, verified) ===================== */
__global__ __launch_bounds__(256) void k_moe(
    const float* __restrict__ yf, const int* __restrict__ taskp,
    const float* __restrict__ wgate,
    const float* __restrict__ w1, const float* __restrict__ b1,
    const float* __restrict__ w2, const float* __restrict__ b2,
    float* __restrict__ px, float* __restrict__ pt,
    double* __restrict__ imp, double* __restrict__ loadc)
{
    __shared__ float yf_sh[4][DR];
    __shared__ float hg_sh[4][2][DH];
    __shared__ float red_sh[8];

    const int tid = threadIdx.x, w = tid >> 6, l = tid & 63;
    if (tid < 8) red_sh[tid] = 0.f;
    const int task = *taskp;
    const int m = blockIdx.x * 4 + w;

    float4 v4 = *(const float4*)(yf + (size_t)m * DR + l * 4);
    *(float4*)&yf_sh[w][l * 4] = v4;
    __syncthreads();

    const float* wg = wgate + task * (DR * NE);
    float lg0 = 0.f, lg1 = 0.f, lg2 = 0.f, lg3 = 0.f;
    {
        const float vv[4] = {v4.x, v4.y, v4.z, v4.w};
#pragma unroll
        for (int i = 0; i < 4; ++i) {
            float4 wrow = *(const float4*)(wg + (l * 4 + i) * 4);
            float a = vv[i];
            lg0 += a * wrow.x; lg1 += a * wrow.y;
            lg2 += a * wrow.z; lg3 += a * wrow.w;
        }
    }
#pragma unroll
    for (int off = 32; off; off >>= 1) {
        lg0 += __shfl_xor(lg0, off); lg1 += __shfl_xor(lg1, off);
        lg2 += __shfl_xor(lg2, off); lg3 += __shfl_xor(lg3, off);
    }
    float lg[4] = {lg0, lg1, lg2, lg3};

    int i0 = 0; float v0 = lg[0];
#pragma unroll
    for (int e = 1; e < 4; ++e) if (lg[e] > v0) { v0 = lg[e]; i0 = e; }
    int i1 = -1; float v1 = -INFINITY;
#pragma unroll
    for (int e = 0; e < 4; ++e) if (e != i0 && lg[e] > v1) { v1 = lg[e]; i1 = e; }
    const float g1 = 1.f / (1.f + expf(v0 - v1));
    const float g0 = 1.f - g1;

    const int half = l >> 5, j = l & 31;
    const int e    = half ? i1 : i0;
    const float ge = half ? g1 : g0;
    const float* w1e = w1 + e * (DR * DH) + j;
    float h = b1[e * DH + j];
#pragma unroll 4
    for (int c = 0; c < DR; c += 4) {
        float4 y4 = *(const float4*)&yf_sh[w][c];
        h += y4.x * w1e[(c + 0) * DH] + y4.y * w1e[(c + 1) * DH]
           + y4.z * w1e[(c + 2) * DH] + y4.w * w1e[(c + 3) * DH];
    }
    hg_sh[w][half][j] = ge * fmaxf(h, 0.f);
    __syncthreads();

    const int o0 = l * 4;
    float4 ym;
    {
        float4 ba = *(const float4*)(b2 + i0 * DR + o0);
        float4 bb = *(const float4*)(b2 + i1 * DR + o0);
        ym.x = g0 * ba.x + g1 * bb.x;
        ym.y = g0 * ba.y + g1 * bb.y;
        ym.z = g0 * ba.z + g1 * bb.z;
        ym.w = g0 * ba.w + g1 * bb.w;
    }
    const float* w2a = w2 + i0 * (DH * DR) + o0;
    const float* w2b = w2 + i1 * (DH * DR) + o0;
#pragma unroll 4
    for (int jj = 0; jj < DH; ++jj) {
        float ha = hg_sh[w][0][jj], hb = hg_sh[w][1][jj];
        float4 wa = *(const float4*)(w2a + jj * DR);
        float4 wb = *(const float4*)(w2b + jj * DR);
        ym.x += ha * wa.x + hb * wb.x;
        ym.y += ha * wa.y + hb * wb.y;
        ym.z += ha * wa.z + hb * wb.z;
        ym.w += ha * wa.w + hb * wb.w;
    }

    float sm = ym.x + ym.y + ym.z + ym.w;
    float sx = (l < 32) ? sm : 0.f;
    float st = (l < 32) ? 0.f : sm;
#pragma unroll
    for (int off = 32; off; off >>= 1) { sx += __shfl_xor(sx, off); st += __shfl_xor(st, off); }
    if (l == 0) {
        px[m] = 1.f / (1.f + expf(-sx * (1.f / 128.f)));
        pt[m] = 1.f / (1.f + expf(-st * (1.f / 128.f)));
        atomicAdd(&red_sh[i0], g0);
        atomicAdd(&red_sh[i1], g1);
        atomicAdd(&red_sh[4 + i0], 1.f);
        atomicAdd(&red_sh[4 + i1], 1.f);
    }
    __syncthreads();
    if (tid < 4)        atomicAdd(&imp[tid], (double)red_sh[tid]);
    else if (tid < 8)   atomicAdd(&loadc[tid - 4], (double)red_sh[tid]);
}

/* =====================  K3: out_x/out_t (shifted-vec stores) + d1/d2  ===================== */
#define K3T 32
__global__ __launch_bounds__(256) void k_outxt(
    const float* __restrict__ x, const float* __restrict__ t,
    const float* __restrict__ past_x, const float* __restrict__ past_t,
    const float* __restrict__ px, const float* __restrict__ pt,
    const int* __restrict__ taskp, const float* __restrict__ mshift,
    float* __restrict__ out_x, float* __restrict__ out_t,
    float* __restrict__ d1, float* __restrict__ d2)
{
    __shared__ float oxs[DIMC], ots[DIMC];
    const int b  = blockIdx.x >> 6;
    const int ch = blockIdx.x & 63;
    const int tid = threadIdx.x;
    const int c  = tid * 4;
    const int task = *taskp;

    float4 shx = *(const float4*)(mshift + (size_t)(task * 2 + 0) * DIMC + c);
    float4 sht = *(const float4*)(mshift + (size_t)(task * 2 + 1) * DIMC + c);

    float a10 = 0.f, a11 = 0.f, a12 = 0.f, a13 = 0.f;
    float a20 = 0.f, a21 = 0.f, a22 = 0.f, a23 = 0.f;
    const int mbase = b * NN + ch * K3T;

    for (int n = 0; n < K3T; ++n) {
        const int m = mbase + n;
        const size_t off = (size_t)m * DIMC + c;
        const float pxv = px[m], ptv = pt[m];

        float4 xv = *(const float4*)(x + off);
        float4 p1 = *(const float4*)(past_x + off);
        float4 ox;
        ox.x = pxv * xv.x + shx.x; ox.y = pxv * xv.y + shx.y;
        ox.z = pxv * xv.z + shx.z; ox.w = pxv * xv.w + shx.w;
        a10 += fabsf(ox.x - p1.x); a11 += fabsf(ox.y - p1.y);
        a12 += fabsf(ox.z - p1.z); a13 += fabsf(ox.w - p1.w);
        *(float4*)&oxs[c] = ox;

        float4 tv = *(const float4*)(t + off);
        float4 p2 = *(const float4*)(past_t + off);
        float4 ot;
        ot.x = ptv * tv.x + sht.x; ot.y = ptv * tv.y + sht.y;
        ot.z = ptv * tv.z + sht.z; ot.w = ptv * tv.w + sht.w;
        a20 += fabsf(ot.x - p2.x); a21 += fabsf(ot.y - p2.y);
        a22 += fabsf(ot.z - p2.z); a23 += fabsf(ot.w - p2.w);
        *(float4*)&ots[c] = ot;
        __syncthreads();

        const size_t rb = (size_t)m * DIMC;
        if (tid < 255) {
            const int cj = 3 + 4 * tid;   /* out_x base is odd: rb+cj is 16B-aligned */
            float4 vx = make_float4(oxs[cj], oxs[cj+1], oxs[cj+2], oxs[cj+3]);
            *(float4*)(out_x + rb + cj) = vx;
            float4 vt = make_float4(ots[cj], ots[cj+1], ots[cj+2], ots[cj+3]);
            *(float4*)(out_t + rb + cj) = vt;
        } else {
            out_x[rb + 0] = oxs[0]; out_x[rb + 1] = oxs[1];
            out_x[rb + 2] = oxs[2]; out_x[rb + 1023] = oxs[1023];
            out_t[rb + 0] = ots[0]; out_t[rb + 1] = ots[1];
            out_t[rb + 2] = ots[2]; out_t[rb + 1023] = ots[1023];
        }
        __syncthreads();
    }
    atomicAdd(&d1[b * DIMC + c + 0], a10);
    atomicAdd(&d1[b * DIMC + c + 1], a11);
    atomicAdd(&d1[b * DIMC + c + 2], a12);
    atomicAdd(&d1[b * DIMC + c + 3], a13);
    atomicAdd(&d2[b * DIMC + c + 0], a20);
    atomicAdd(&d2[b * DIMC + c + 1], a21);
    atomicAdd(&d2[b * DIMC + c + 2], a22);
    atomicAdd(&d2[b * DIMC + c + 3], a23);
}

/* =====================  K5: score-net, parallel over j-chunks  ===================== */
__global__ __launch_bounds__(256) void k_score(
    const float* __restrict__ d1, const float* __restrict__ d2,
    const float* __restrict__ ws1, const float* __restrict__ ws2,
    float* __restrict__ sv)
{
    __shared__ float red1[4][64], red2[4][64];
    const int tid = threadIdx.x;
    const int b = blockIdx.x >> 4, jc = blockIdx.x & 15;
    const int j = jc * 64 + (tid & 63), part = tid >> 6;
    const float* d1r = d1 + b * DIMC + part * 256;
    const float* d2r = d2 + b * DIMC + part * 256;
    const float* wp  = ws1 + (size_t)(part * 256) * DIMC + j;

    float acc1 = 0.f, acc2 = 0.f;
    for (int i = 0; i < 256; ++i) {
        float w = wp[(size_t)i * DIMC];
        acc1 += d1r[i] * w;
        acc2 += d2r[i] * w;
    }
    red1[part][tid & 63] = acc1;
    red2[part][tid & 63] = acc2;
    __syncthreads();
    if (tid < 64) {
        float h1 = red1[0][tid] + red1[1][tid] + red1[2][tid] + red1[3][tid];
        float h2 = red2[0][tid] + red2[1][tid] + red2[2][tid] + red2[3][tid];
        const int jj = jc * 64 + tid;
        float s1 = fmaxf(h1 * (1.f / NN), 0.f) * ws2[jj];
        float s2 = fmaxf(h2 * (1.f / NN), 0.f) * ws2[jj];
#pragma unroll
        for (int mask = 1; mask <= 32; mask <<= 1) {
            s1 += __shfl_xor(s1, mask); s2 += __shfl_xor(s2, mask);
        }
        if (tid == 0) {
            atomicAdd(&sv[b * 2 + 0], s1);
            atomicAdd(&sv[b * 2 + 1], s2);
        }
    }
}

/* =====================  K6: aux_loss + softmax combine weights  ===================== */
__global__ void k_final_small(const double* __restrict__ imp, const double* __restrict__ loadc,
                              const float* __restrict__ sv, float* __restrict__ wcomb,
                              float* __restrict__ aux_out)
{
    const int tid = threadIdx.x;
    if (tid == 0) {
        double mi = 0, qi = 0, ml = 0, ql = 0;
        for (int e = 0; e < 4; ++e) {
            mi += imp[e]; qi += imp[e] * imp[e];
            ml += loadc[e]; ql += loadc[e] * loadc[e];
        }
        mi *= 0.25; qi *= 0.25; ml *= 0.25; ql *= 0.25;
        double vi = qi - mi * mi, vl = ql - ml * ml;
        *aux_out = (float)(vi / (mi * mi + 1e-10) + vl / (ml * ml + 1e-10));
    }
    if (tid < 8) {
        float s1 = sv[tid * 2 + 0], s2 = sv[tid * 2 + 1];
        float mx = fmaxf(s1, s2);
        float e1 = expf(s1 - mx), e2 = expf(s2 - mx);
        float inv = 1.f / (e1 + e2);
        wcomb[tid * 2 + 0] = e2 * inv;   /* w[:,1] → multiplies out_x */
        wcomb[tid * 2 + 1] = e1 * inv;   /* w[:,0] → multiplies out_t */
    }
}

/* =====================  K7: final combine (shifted-vec reads)  ===================== */
__global__ __launch_bounds__(256) void k_combine(
    const float* __restrict__ out_x, const float* __restrict__ out_t,
    const float* __restrict__ wcomb, float* __restrict__ out)
{
    __shared__ float oxs[DIMC], ots[DIMC];
    const int m = blockIdx.x;
    const size_t rb = (size_t)m * DIMC;
    const int b = m >> 11;
    const float wx = wcomb[b * 2 + 0], wt = wcomb[b * 2 + 1];
    const int tid = threadIdx.x;

    if (tid < 255) {
        const int cj = 3 + 4 * tid;
        float4 vx = *(const float4*)(out_x + rb + cj);
        oxs[cj] = vx.x; oxs[cj + 1] = vx.y; oxs[cj + 2] = vx.z; oxs[cj + 3] = vx.w;
        float4 vt = *(const float4*)(out_t + rb + cj);
        ots[cj] = vt.x; ots[cj + 1] = vt.y; ots[cj + 2] = vt.z; ots[cj + 3] = vt.w;
    } else {
        oxs[0] = out_x[rb + 0]; oxs[1] = out_x[rb + 1];
        oxs[2] = out_x[rb + 2]; oxs[1023] = out_x[rb + 1023];
        ots[0] = out_t[rb + 0]; ots[1] = out_t[rb + 1];
        ots[2] = out_t[rb + 2]; ots[1023] = out_t[rb + 1023];
    }
    __syncthreads();

    const int c = tid * 4;
    float4 o;
    o.x = wx * oxs[c + 0] + wt * ots[c + 0];
    o.y = wx * oxs[c + 1] + wt * ots[c + 1];
    o.z = wx * oxs[c + 2] + wt * ots[c + 2];
    o.w = wx * oxs[c + 3] + wt * ots[c + 3];
    *(float4*)(out + rb + c) = o;
}

/* =====================  launch  ===================== */
extern "C" void kernel_launch(void* const* d_in, const int* in_sizes, int n_in,
                              void* d_out, int out_size, void* d_ws, size_t ws_size,
                              hipStream_t stream)
{
    const float* x      = (const float*)d_in[0];
    const float* t      = (const float*)d_in[1];
    const float* past_x = (const float*)d_in[2];
    const float* past_t = (const float*)d_in[3];
    const int*   task   = (const int*)d_in[4];
    const float* ln1g   = (const float*)d_in[5];
    const float* ln1b   = (const float*)d_in[6];
    const float* wred   = (const float*)d_in[7];
    const float* ln2g   = (const float*)d_in[8];
    const float* ln2b   = (const float*)d_in[9];
    const float* wgate  = (const float*)d_in[10];
    const float* w1     = (const float*)d_in[11];
    const float* b1     = (const float*)d_in[12];
    const float* w2     = (const float*)d_in[13];
    const float* b2     = (const float*)d_in[14];
    const float* mshift = (const float*)d_in[15];
    const float* ws1    = (const float*)d_in[16];
    const float* ws2    = (const float*)d_in[17];

    /* small accumulators in d_ws (65,728 B — known-safe) */
    float* f     = (float*)d_ws;
    float* d1    = f;
    float* d2    = f + 8192;
    float* sv    = f + 16384;
    float* wcomb = f + 16400;
    double* imp   = (double*)(f + 16416);
    double* loadc = (double*)(f + 16424);

    float* out   = (float*)d_out;
    float* aux   = out + (size_t)NM * DIMC;
    float* out_x = aux + 1;                       /* odd float offset */
    float* out_t = out_x + (size_t)NM * DIMC;

    /* big scratch inside `out` region (dead before k_combine writes it):
       yf [0, 4194304) · W'' bf16 at float 8,000,000 (262,144 floats) ·
       u/beta at 8,400,000 (512 floats) · px/pt parked at region tail */
    float* yf  = out;
    unsigned short* wpp = (unsigned short*)(out + 8000000);
    float* u    = out + 8400000;
    float* beta = out + 8400256;
    float* px   = out + (size_t)NM * DIMC - 2 * NM;   /* 16,744,448 */
    float* pt   = px + NM;

    hipMemsetAsync(d_ws, 0, 16432 * sizeof(float), stream);
    hipMemsetAsync(u, 0, 512 * sizeof(float), stream);

    k_prep<<<128, 256, 0, stream>>>(wred, ln1g, ln1b, wpp, u, beta);
    k_front<<<NM / FT, 256, 0, stream>>>(x, t, wpp, u, beta, ln2g, ln2b, yf);
    k_moe<<<NM / 4, 256, 0, stream>>>(yf, task, wgate, w1, b1, w2, b2, px, pt, imp, loadc);
    k_outxt<<<NB * (NN / K3T), 256, 0, stream>>>(x, t, past_x, past_t, px, pt, task,
                                                 mshift, out_x, out_t, d1, d2);
    k_score<<<128, 256, 0, stream>>>(d1, d2, ws1, ws2, sv);
    k_final_small<<<1, 64, 0, stream>>>(imp, loadc, sv, wcomb, aux);
    k_combine<<<NM, 256, 0, stream>>>(out_x, out_t, wcomb, out);
}